// Round 5
// baseline (19736.942 us; speedup 1.0000x reference)
//
#include <hip/hip_runtime.h>
#include <hip/hip_bf16.h>
#include <math.h>

// ---------------------------------------------------------------------------
// Naive 3x3 SAME conv, NCHW. One thread per output element, f64 accumulate.
// ---------------------------------------------------------------------------
template <int CIN, bool RELU>
__global__ __launch_bounds__(256) void conv_naive(
    const float* __restrict__ in, const float* __restrict__ wgt,
    const float* __restrict__ bias, float* __restrict__ out, int cout) {
  int idx = blockIdx.x * 256 + threadIdx.x;  // ((b*cout+co)*32+h)*32+w
  int total = 32 * cout * 1024;
  if (idx >= total) return;
  int w = idx & 31;
  int h = (idx >> 5) & 31;
  int co = (idx >> 10) % cout;
  int b = idx / (1024 * cout);
  double acc = (double)bias[co];
  for (int ci = 0; ci < CIN; ++ci) {
    for (int kh = 0; kh < 3; ++kh) {
      int hh = h + kh - 1;
      if (hh < 0 || hh >= 32) continue;
      for (int kw = 0; kw < 3; ++kw) {
        int ww = w + kw - 1;
        if (ww < 0 || ww >= 32) continue;
        acc += (double)in[((b * CIN + ci) * 32 + hh) * 32 + ww] *
               (double)wgt[((co * CIN + ci) * 3 + kh) * 3 + kw];
      }
    }
  }
  float o = (float)acc;
  if (RELU) o = fmaxf(o, 0.f);
  out[idx] = o;
}

// ---------------------------------------------------------------------------
// Fused conv5 (64->256, no relu) + LayerNorm(256) + K/V projection (256->64
// each). One block per (b, pixel); 256 threads = 256 output channels.
// Never materializes feats -> cuts workspace peak to ~26 MB.
// ---------------------------------------------------------------------------
__global__ __launch_bounds__(256) void conv5_ln_kv(
    const float* __restrict__ in,    // (B,64,32,32) conv4 output
    const float* __restrict__ wgt,   // enc_wo (256,64,3,3)
    const float* __restrict__ bias,  // enc_bo (256)
    const float* __restrict__ wk, const float* __restrict__ wv,
    float* __restrict__ kout, float* __restrict__ vout) {
  int bp = blockIdx.x;  // b*1024 + p
  int b = bp >> 10, p = bp & 1023;
  int h = p >> 5, w = p & 31;
  int c = threadIdx.x;  // output channel
  __shared__ double xn[256];
  __shared__ double red[256];
  double acc = (double)bias[c];
  for (int ci = 0; ci < 64; ++ci) {
    for (int kh = 0; kh < 3; ++kh) {
      int hh = h + kh - 1;
      if (hh < 0 || hh >= 32) continue;
      for (int kw = 0; kw < 3; ++kw) {
        int ww = w + kw - 1;
        if (ww < 0 || ww >= 32) continue;
        acc += (double)in[((b * 64 + ci) * 32 + hh) * 32 + ww] *
               (double)wgt[((c * 64 + ci) * 3 + kh) * 3 + kw];
      }
    }
  }
  red[c] = acc;
  __syncthreads();
  for (int st = 128; st > 0; st >>= 1) {
    if (c < st) red[c] += red[c + st];
    __syncthreads();
  }
  double m = red[0] * (1.0 / 256.0);
  __syncthreads();
  double dv = acc - m;
  red[c] = dv * dv;
  __syncthreads();
  for (int st = 128; st > 0; st >>= 1) {
    if (c < st) red[c] += red[c + st];
    __syncthreads();
  }
  double isd = 1.0 / sqrt(red[0] * (1.0 / 256.0) + 1e-5);
  __syncthreads();
  xn[c] = dv * isd;
  __syncthreads();
  if (c < 128) {
    const float* wb = (c < 64) ? wk : wv;
    int d = c & 63;
    double a2 = 0.0;
    for (int cc = 0; cc < 256; ++cc) a2 += xn[cc] * (double)wb[cc * 64 + d];
    float* ob = (c < 64) ? kout : vout;
    ob[(b * 1024 + p) * 64 + d] = (float)a2;
  }
}

// ---------------------------------------------------------------------------
// Slot init + first q. Block per (b,s) = 224 blocks, 64 threads.
// ---------------------------------------------------------------------------
__global__ __launch_bounds__(64) void slot_init(
    const float* __restrict__ mu, const float* __restrict__ logsig,
    const float* __restrict__ noise, const float* __restrict__ wq,
    double* __restrict__ slots, double* __restrict__ qbuf) {
  int bs = blockIdx.x;
  int d = threadIdx.x;
  int sr = bs % 7;
  __shared__ double ln[64], red[64];
  double s = (double)mu[sr * 64 + d] +
             (double)noise[bs * 64 + d] * exp((double)logsig[sr * 64 + d]);
  slots[bs * 64 + d] = s;
  red[d] = s;
  __syncthreads();
  for (int st = 32; st > 0; st >>= 1) {
    if (d < st) red[d] += red[d + st];
    __syncthreads();
  }
  double m = red[0] * (1.0 / 64.0);
  __syncthreads();
  double dv = s - m;
  red[d] = dv * dv;
  __syncthreads();
  for (int st = 32; st > 0; st >>= 1) {
    if (d < st) red[d] += red[d + st];
    __syncthreads();
  }
  double isd = 1.0 / sqrt(red[0] * (1.0 / 64.0) + 1e-5);
  __syncthreads();
  ln[d] = dv * isd;
  __syncthreads();
  double q = 0.0;
  for (int dd = 0; dd < 64; ++dd) q += ln[dd] * (double)wq[dd * 64 + d];
  qbuf[bs * 64 + d] = q * 0.125;
}

// ---------------------------------------------------------------------------
// Attention logits + softmax over s (+1e-8). One thread per (b,n).
// ---------------------------------------------------------------------------
__global__ __launch_bounds__(256) void attn_softmax(
    const float* __restrict__ kbuf, const double* __restrict__ qbuf,
    double* __restrict__ attw) {
  int idx = blockIdx.x * 256 + threadIdx.x;  // b*1024+n
  if (idx >= 32 * 1024) return;
  int b = idx >> 10;
  double l[7];
  for (int s = 0; s < 7; ++s) {
    double acc = 0.0;
    for (int d = 0; d < 64; ++d)
      acc += (double)kbuf[idx * 64 + d] * qbuf[(b * 7 + s) * 64 + d];
    l[s] = acc;
  }
  double mx = l[0];
  for (int s = 1; s < 7; ++s) mx = fmax(mx, l[s]);
  double sum = 0.0;
  for (int s = 0; s < 7; ++s) {
    l[s] = exp(l[s] - mx);
    sum += l[s];
  }
  double inv = 1.0 / sum;
  for (int s = 0; s < 7; ++s) attw[idx * 7 + s] = l[s] * inv + 1e-8;
}

// ---------------------------------------------------------------------------
// Weighted-mean updates. Block per (b,s), 64 threads (d).
// ---------------------------------------------------------------------------
__global__ __launch_bounds__(64) void attn_updates(
    const double* __restrict__ attw, const float* __restrict__ vbuf,
    double* __restrict__ upd) {
  int bs = blockIdx.x;
  int b = bs / 7, s = bs % 7;
  int d = threadIdx.x;
  __shared__ double red[64];
  double ps = 0.0;
  for (int n = d; n < 1024; n += 64) ps += attw[(b * 1024 + n) * 7 + s];
  red[d] = ps;
  __syncthreads();
  for (int st = 32; st > 0; st >>= 1) {
    if (d < st) red[d] += red[d + st];
    __syncthreads();
  }
  double asum = red[0];
  double acc = 0.0;
  for (int n = 0; n < 1024; ++n)
    acc += attw[(b * 1024 + n) * 7 + s] * (double)vbuf[(b * 1024 + n) * 64 + d];
  upd[bs * 64 + d] = acc / asum;
}

// ---------------------------------------------------------------------------
// GRU + residual MLP + next q. Block per (b,s), 64 threads.
// ---------------------------------------------------------------------------
__global__ __launch_bounds__(64) void slot_update(
    const double* __restrict__ upd, const float* __restrict__ gwi,
    const float* __restrict__ gwh, const float* __restrict__ gb,
    const float* __restrict__ w1, const float* __restrict__ b1,
    const float* __restrict__ w2, const float* __restrict__ b2,
    const float* __restrict__ wq, double* __restrict__ slots,
    double* __restrict__ qbuf) {
  int bs = blockIdx.x;
  int d = threadIdx.x;
  __shared__ double u[64], p[64], ln[64], h[128], red[64];
  u[d] = upd[bs * 64 + d];
  p[d] = slots[bs * 64 + d];
  __syncthreads();
  double giz = (double)gb[d], gir = (double)gb[64 + d], gin = (double)gb[128 + d];
  double ghz = 0.0, ghr = 0.0, ghn = 0.0;
  for (int dd = 0; dd < 64; ++dd) {
    giz += u[dd] * (double)gwi[dd * 192 + d];
    gir += u[dd] * (double)gwi[dd * 192 + 64 + d];
    gin += u[dd] * (double)gwi[dd * 192 + 128 + d];
    ghz += p[dd] * (double)gwh[dd * 192 + d];
    ghr += p[dd] * (double)gwh[dd * 192 + 64 + d];
    ghn += p[dd] * (double)gwh[dd * 192 + 128 + d];
  }
  double z = 1.0 / (1.0 + exp(-(giz + ghz)));
  double r = 1.0 / (1.0 + exp(-(gir + ghr)));
  double nn = tanh(gin + r * ghn);
  double s = (1.0 - z) * nn + z * p[d];
  red[d] = s;
  __syncthreads();
  for (int st = 32; st > 0; st >>= 1) {
    if (d < st) red[d] += red[d + st];
    __syncthreads();
  }
  double m = red[0] * (1.0 / 64.0);
  __syncthreads();
  double dv = s - m;
  red[d] = dv * dv;
  __syncthreads();
  for (int st = 32; st > 0; st >>= 1) {
    if (d < st) red[d] += red[d + st];
    __syncthreads();
  }
  double isd = 1.0 / sqrt(red[0] * (1.0 / 64.0) + 1e-5);
  __syncthreads();
  ln[d] = dv * isd;
  __syncthreads();
  double h0 = (double)b1[d], h1 = (double)b1[64 + d];
  for (int dd = 0; dd < 64; ++dd) {
    h0 += ln[dd] * (double)w1[dd * 128 + d];
    h1 += ln[dd] * (double)w1[dd * 128 + 64 + d];
  }
  h[d] = fmax(h0, 0.0);
  h[64 + d] = fmax(h1, 0.0);
  __syncthreads();
  double o = (double)b2[d];
  for (int e = 0; e < 128; ++e) o += h[e] * (double)w2[e * 64 + d];
  double s2 = s + o;
  slots[bs * 64 + d] = s2;
  red[d] = s2;
  __syncthreads();
  for (int st = 32; st > 0; st >>= 1) {
    if (d < st) red[d] += red[d + st];
    __syncthreads();
  }
  double m2 = red[0] * (1.0 / 64.0);
  __syncthreads();
  double dv2 = s2 - m2;
  red[d] = dv2 * dv2;
  __syncthreads();
  for (int st = 32; st > 0; st >>= 1) {
    if (d < st) red[d] += red[d + st];
    __syncthreads();
  }
  double isd2 = 1.0 / sqrt(red[0] * (1.0 / 64.0) + 1e-5);
  __syncthreads();
  ln[d] = dv2 * isd2;
  __syncthreads();
  double q = 0.0;
  for (int dd = 0; dd < 64; ++dd) q += ln[dd] * (double)wq[dd * 64 + d];
  qbuf[bs * 64 + d] = q * 0.125;
}

// ---------------------------------------------------------------------------
// Estimator scores. One thread per (b,s,a).
// ---------------------------------------------------------------------------
__global__ __launch_bounds__(256) void scores_naive(
    const double* __restrict__ slots, const float* __restrict__ we,
    const float* __restrict__ wd, double* __restrict__ sc) {
  int idx = blockIdx.x * 256 + threadIdx.x;  // bs*50 + a
  if (idx >= 224 * 50) return;
  int a = idx % 50, bs = idx / 50;
  double lat[32];
  for (int z = 0; z < 32; ++z) {
    double acc = 0.0;
    for (int dd = 0; dd < 64; ++dd)
      acc += slots[bs * 64 + dd] * (double)we[(a * 64 + dd) * 32 + z];
    lat[z] = acc;
  }
  double sum = 0.0;
  for (int dd = 0; dd < 64; ++dd) {
    double rec = 0.0;
    for (int z = 0; z < 32; ++z) rec += lat[z] * (double)wd[(a * 32 + z) * 64 + dd];
    double df = rec - slots[bs * 64 + dd];
    sum += df * df;
  }
  sc[idx] = -sum;
}

// ---------------------------------------------------------------------------
// Top-3 per (b,s), serial, lowest-index tie-break. One thread per bs.
// ---------------------------------------------------------------------------
__global__ __launch_bounds__(256) void topk_naive(const double* __restrict__ sc,
                                                  int* __restrict__ topk) {
  int bs = blockIdx.x * 256 + threadIdx.x;
  if (bs >= 224) return;
  int chosen[3];
  for (int r = 0; r < 3; ++r) {
    double best = -1e300;
    int bi = -1;
    for (int a = 0; a < 50; ++a) {
      bool skip = false;
      for (int rr = 0; rr < r; ++rr)
        if (chosen[rr] == a) skip = true;
      if (skip) continue;
      double v = sc[bs * 50 + a];
      if (v > best) {
        best = v;
        bi = a;
      }
    }
    chosen[r] = bi;
    topk[bs * 3 + r] = bi;
  }
}

// ---------------------------------------------------------------------------
// Expert MLP, one block per token (672 blocks, 256 threads), f64 LDS h.
// ---------------------------------------------------------------------------
__global__ __launch_bounds__(256) void expert_naive(
    const int* __restrict__ topk, const double* __restrict__ slots,
    const float* __restrict__ win, const float* __restrict__ bin,
    const float* __restrict__ wblk, const float* __restrict__ bblk,
    const float* __restrict__ wout, const float* __restrict__ bout,
    float* __restrict__ outp) {
  int ti = blockIdx.x;  // (b*7+s)*3 + kk
  int a = topk[ti];
  int bs = ti / 3;
  int t = threadIdx.x;
  __shared__ double tok[64], ha[256], hb[256];
  if (t < 64) tok[t] = slots[bs * 64 + t];
  __syncthreads();
  double acc = (double)bin[a * 256 + t];
  for (int dd = 0; dd < 64; ++dd)
    acc += tok[dd] * (double)win[(a * 64 + dd) * 256 + t];
  ha[t] = fmax(acc, 0.0);
  __syncthreads();
  double* cur = ha;
  double* nxt = hb;
  for (int i = 0; i < 3; ++i) {
    double a2 = cur[t] + (double)bblk[(a * 3 + i) * 256 + t];
    for (int hh = 0; hh < 256; ++hh)
      a2 += cur[hh] * (double)wblk[((a * 3 + i) * 256 + hh) * 256 + t];
    nxt[t] = fmax(a2, 0.0);
    __syncthreads();
    double* tmp = cur;
    cur = nxt;
    nxt = tmp;
  }
  if (t < 128) {
    double a3 = (double)bout[a * 128 + t];
    for (int hh = 0; hh < 256; ++hh)
      a3 += cur[hh] * (double)wout[(a * 256 + hh) * 128 + t];
    outp[ti * 128 + t] = (float)a3;
  }
}

// ---------------------------------------------------------------------------
extern "C" void kernel_launch(void* const* d_in, const int* in_sizes, int n_in,
                              void* d_out, int out_size, void* d_ws,
                              size_t ws_size, hipStream_t stream) {
  (void)in_sizes; (void)n_in; (void)out_size; (void)ws_size;
  const float* images = (const float*)d_in[0];
  const float* noise = (const float*)d_in[1];
  const float* enc_w0 = (const float*)d_in[2];
  const float* enc_b0 = (const float*)d_in[3];
  const float* enc_w = (const float*)d_in[4];
  const float* enc_b = (const float*)d_in[5];
  const float* enc_wo = (const float*)d_in[6];
  const float* enc_bo = (const float*)d_in[7];
  const float* wk = (const float*)d_in[8];
  const float* wv = (const float*)d_in[9];
  const float* wq = (const float*)d_in[10];
  const float* gru_wi = (const float*)d_in[11];
  const float* gru_wh = (const float*)d_in[12];
  const float* gru_b = (const float*)d_in[13];
  const float* mlp_w1 = (const float*)d_in[14];
  const float* mlp_b1 = (const float*)d_in[15];
  const float* mlp_w2 = (const float*)d_in[16];
  const float* mlp_b2 = (const float*)d_in[17];
  const float* mu = (const float*)d_in[18];
  const float* logsig = (const float*)d_in[19];
  const float* est_we = (const float*)d_in[20];
  const float* est_wd = (const float*)d_in[21];
  const float* ag_win = (const float*)d_in[22];
  const float* ag_bin = (const float*)d_in[23];
  const float* ag_wblk = (const float*)d_in[24];
  const float* ag_bblk = (const float*)d_in[25];
  const float* ag_wout = (const float*)d_in[26];
  const float* ag_bout = (const float*)d_in[27];

  // Workspace layout (~26.2 MB total; doubles first for alignment):
  double* dws = (double*)d_ws;
  double* slots = dws;                  // 14336
  double* qbuf = slots + 14336;         // 14336
  double* upd = qbuf + 14336;           // 14336
  double* attw = upd + 14336;           // 229376
  double* sc = attw + 229376;           // 11200
  int* topk = (int*)(sc + 11200);       // 672 (pad to 1024)
  float* xA = (float*)(topk + 1024);    // 2097152 floats
  float* xB = xA + 2097152;             // 2097152
  float* vbuf = xB + 2097152;           // 2097152

  conv_naive<3, true><<<8192, 256, 0, stream>>>(images, enc_w0, enc_b0, xA, 64);
  conv_naive<64, true><<<8192, 256, 0, stream>>>(xA, enc_w, enc_b, xB, 64);
  conv_naive<64, true><<<8192, 256, 0, stream>>>(xB, enc_w + 36864, enc_b + 64, xA, 64);
  conv_naive<64, true><<<8192, 256, 0, stream>>>(xA, enc_w + 73728, enc_b + 128, xB, 64);
  // fused conv5 + LN + K/V: reads xB, writes k->xA, v->vbuf
  conv5_ln_kv<<<32768, 256, 0, stream>>>(xB, enc_wo, enc_bo, wk, wv, xA, vbuf);
  slot_init<<<224, 64, 0, stream>>>(mu, logsig, noise, wq, slots, qbuf);
  for (int it = 0; it < 3; ++it) {
    attn_softmax<<<128, 256, 0, stream>>>(xA, qbuf, attw);
    attn_updates<<<224, 64, 0, stream>>>(attw, vbuf, upd);
    slot_update<<<224, 64, 0, stream>>>(upd, gru_wi, gru_wh, gru_b, mlp_w1,
                                        mlp_b1, mlp_w2, mlp_b2, wq, slots, qbuf);
  }
  scores_naive<<<44, 256, 0, stream>>>(slots, est_we, est_wd, sc);
  topk_naive<<<1, 256, 0, stream>>>(sc, topk);
  expert_naive<<<672, 256, 0, stream>>>(topk, slots, ag_win, ag_bin, ag_wblk,
                                        ag_bblk, ag_wout, ag_bout,
                                        (float*)d_out);
}

// Round 8
// 2164.654 us; speedup vs baseline: 9.1178x; 9.1178x over previous
//
#include <hip/hip_runtime.h>
#include <hip/hip_bf16.h>
#include <math.h>

// ---------------------------------------------------------------------------
// Tiled 3x3 SAME conv, NCHW, stride 1. f32 storage, f64 accumulation.
// Block = 256 thr covers (b, 4 h-rows, 64 co). Thread tile: 8 co x 4 w.
// LDS: s_in 13.4KB + s_w 36.9KB = 50.3KB  (< 64KB limit!)
// ---------------------------------------------------------------------------
template <int CIN, bool RELU>
__global__ __launch_bounds__(256) void conv3x3_kernel(
    const float* __restrict__ in, const float* __restrict__ wgt,
    const float* __restrict__ bias, float* __restrict__ out,
    int cout_total, int cb_count) {
  constexpr int CHUNK = (CIN < 16) ? CIN : 16;
  __shared__ float s_in[6 * CHUNK * 35];
  __shared__ float s_w[CHUNK * 9 * 64];
  int bx = blockIdx.x;
  int cb = bx % cb_count;
  bx /= cb_count;
  int hb = bx & 7;
  int b = bx >> 3;
  int co_base = cb * 64;
  int t = threadIdx.x;
  int w_g = t & 7, co_g = (t >> 3) & 7, h_l = t >> 6;
  int h0 = hb * 4;
  int w0 = w_g * 4;
  double acc[8][4];
#pragma unroll
  for (int j = 0; j < 8; ++j)
#pragma unroll
    for (int ww = 0; ww < 4; ++ww) acc[j][ww] = 0.0;

  for (int cc = 0; cc < CIN; cc += CHUNK) {
    __syncthreads();
    for (int i = t; i < 6 * CHUNK * 32; i += 256) {
      int r = i / (CHUNK * 32);
      int c = (i >> 5) % CHUNK;
      int w = i & 31;
      int gh = h0 - 1 + r;
      float v = 0.f;
      if (gh >= 0 && gh < 32) v = in[((b * CIN + cc + c) * 32 + gh) * 32 + w];
      s_in[(r * CHUNK + c) * 35 + w + 1] = v;
    }
    for (int i = t; i < 6 * CHUNK; i += 256) {
      s_in[i * 35] = 0.f;
      s_in[i * 35 + 33] = 0.f;
    }
    for (int i = t; i < CHUNK * 9 * 64; i += 256) {
      int co = i / (CHUNK * 9);
      int rem = i % (CHUNK * 9);
      s_w[rem * 64 + co] = wgt[((co_base + co) * CIN + cc) * 9 + rem];
    }
    __syncthreads();
    for (int c = 0; c < CHUNK; ++c) {
#pragma unroll
      for (int kh = 0; kh < 3; ++kh) {
        const float* ip = &s_in[((h_l + kh) * CHUNK + c) * 35 + w0];
        double ivd[6];
#pragma unroll
        for (int j = 0; j < 6; ++j) ivd[j] = (double)ip[j];
        const float* wp = &s_w[(c * 9 + kh * 3) * 64 + co_g * 8];
#pragma unroll
        for (int kw = 0; kw < 3; ++kw) {
          float4 wa = *(const float4*)(wp + kw * 64);
          float4 wb = *(const float4*)(wp + kw * 64 + 4);
          double wrd[8] = {(double)wa.x, (double)wa.y, (double)wa.z,
                           (double)wa.w, (double)wb.x, (double)wb.y,
                           (double)wb.z, (double)wb.w};
#pragma unroll
          for (int j = 0; j < 8; ++j)
#pragma unroll
            for (int ww = 0; ww < 4; ++ww)
              acc[j][ww] = fma(ivd[kw + ww], wrd[j], acc[j][ww]);
        }
      }
    }
  }
  int h = h0 + h_l;
#pragma unroll
  for (int j = 0; j < 8; ++j) {
    int co = co_base + co_g * 8 + j;
    double bv = (double)bias[co];
    float4 o;
    o.x = (float)(acc[j][0] + bv);
    o.y = (float)(acc[j][1] + bv);
    o.z = (float)(acc[j][2] + bv);
    o.w = (float)(acc[j][3] + bv);
    if (RELU) {
      o.x = fmaxf(o.x, 0.f);
      o.y = fmaxf(o.y, 0.f);
      o.z = fmaxf(o.z, 0.f);
      o.w = fmaxf(o.w, 0.f);
    }
    *(float4*)(&out[((b * cout_total + co) * 32 + h) * 32 + w0]) = o;
  }
}

// ---------------------------------------------------------------------------
// Fused conv5 (64->256) + LayerNorm(256) + K/V projection. Tiled.
// Block = (b, 16 contiguous pixels of one row); 256 thr = 16 px x 16 co-grps.
// Weights LDS-staged in ci-chunks of 2. f64 accumulation throughout.
// LDS: s_w 18.4KB + s_xn 33KB + s_red 2.2KB + misc = 54.4KB (< 64KB).
// ---------------------------------------------------------------------------
__global__ __launch_bounds__(256) void conv5_ln_kv_fused(
    const float* __restrict__ in,    // (B,64,32,32)
    const float* __restrict__ wgt,   // (256,64,3,3)
    const float* __restrict__ bias,  // (256)
    const float* __restrict__ wk, const float* __restrict__ wv,
    float* __restrict__ kout, float* __restrict__ vout) {
  int bp = blockIdx.x;            // b*64 + pt
  int b = bp >> 6, pt = bp & 63;  // 64 pixel-tiles of 16
  int h = pt >> 1, w0 = (pt & 1) * 16;
  int t = threadIdx.x;
  int px = t & 15, cg = t >> 4;  // co = cg*16 + j

  __shared__ float s_w[2 * 9 * 256];
  __shared__ float s_in[2][3][20];
  __shared__ double s_red[16][17];
  __shared__ double s_m[16], s_isd[16];
  __shared__ double s_xn[16][258];  // padded: stride 258 -> <=2-way conflicts

  double acc[16];
#pragma unroll
  for (int j = 0; j < 16; ++j) acc[j] = 0.0;

  for (int cc = 0; cc < 64; cc += 2) {
    __syncthreads();
    // stage weights: s_w[(c*9+k)*256 + co] = wgt[(co*64+cc+c)*9 + k]
    for (int i = t; i < 2 * 9 * 256; i += 256) {
      int co = i & 255;   // == t
      int rem = i >> 8;   // 0..17
      int c = rem / 9, k = rem % 9;
      s_w[(c * 9 + k) * 256 + co] = wgt[(co * 64 + cc + c) * 9 + k];
    }
    // stage input: 2 ci x 3 rows x 18 cols (halo zero-padded)
    for (int i = t; i < 2 * 3 * 18; i += 256) {
      int c = i / 54;
      int r = (i / 18) % 3;
      int cw = i % 18;
      int gh = h + r - 1;
      int gw = w0 + cw - 1;
      float v = 0.f;
      if (gh >= 0 && gh < 32 && gw >= 0 && gw < 32)
        v = in[((b * 64 + cc + c) * 32 + gh) * 32 + gw];
      s_in[c][r][cw] = v;
    }
    __syncthreads();
#pragma unroll
    for (int c = 0; c < 2; ++c) {
#pragma unroll
      for (int kh = 0; kh < 3; ++kh) {
        double iv[3];
#pragma unroll
        for (int kw = 0; kw < 3; ++kw) iv[kw] = (double)s_in[c][kh][px + kw];
        const float* wp = &s_w[(c * 9 + kh * 3) * 256 + cg * 16];
#pragma unroll
        for (int kw = 0; kw < 3; ++kw) {
#pragma unroll
          for (int j = 0; j < 16; ++j)
            acc[j] = fma(iv[kw], (double)wp[kw * 256 + j], acc[j]);
        }
      }
    }
  }
  // bias + LayerNorm over 256 channels of pixel px
#pragma unroll
  for (int j = 0; j < 16; ++j) acc[j] += (double)bias[cg * 16 + j];
  double psum = 0.0;
#pragma unroll
  for (int j = 0; j < 16; ++j) psum += acc[j];
  s_red[px][cg] = psum;
  __syncthreads();
  if (t < 16) {
    double m = 0.0;
    for (int g = 0; g < 16; ++g) m += s_red[t][g];
    s_m[t] = m * (1.0 / 256.0);
  }
  __syncthreads();
  double m = s_m[px];
  double vp = 0.0;
#pragma unroll
  for (int j = 0; j < 16; ++j) {
    double dv = acc[j] - m;
    vp += dv * dv;
  }
  s_red[px][cg] = vp;
  __syncthreads();
  if (t < 16) {
    double v = 0.0;
    for (int g = 0; g < 16; ++g) v += s_red[t][g];
    s_isd[t] = 1.0 / sqrt(v * (1.0 / 256.0) + 1e-5);
  }
  __syncthreads();
  double isd = s_isd[px];
#pragma unroll
  for (int j = 0; j < 16; ++j) s_xn[px][cg * 16 + j] = (acc[j] - m) * isd;
  __syncthreads();
  // K/V projection: thread -> (px, col_g); col_g 0..7 -> k cols, 8..15 -> v
  int col0 = cg * 8;
  const float* wb = (cg < 8) ? wk : wv;
  int d0 = col0 & 63;
  double a2[8];
#pragma unroll
  for (int j = 0; j < 8; ++j) a2[j] = 0.0;
  for (int c = 0; c < 256; ++c) {
    double xv = s_xn[px][c];
    const float* wr = &wb[c * 64 + d0];
#pragma unroll
    for (int j = 0; j < 8; ++j) a2[j] = fma(xv, (double)wr[j], a2[j]);
  }
  int p = h * 32 + w0 + px;
  float* ob = (cg < 8) ? kout : vout;
#pragma unroll
  for (int j = 0; j < 8; ++j) ob[(b * 1024 + p) * 64 + d0 + j] = (float)a2[j];
}

// ---------------------------------------------------------------------------
// Slot init + first q. Block per (b,s) = 224 blocks, 64 threads.
// ---------------------------------------------------------------------------
__global__ __launch_bounds__(64) void slot_init(
    const float* __restrict__ mu, const float* __restrict__ logsig,
    const float* __restrict__ noise, const float* __restrict__ wq,
    double* __restrict__ slots, double* __restrict__ qbuf) {
  int bs = blockIdx.x;
  int d = threadIdx.x;
  int sr = bs % 7;
  __shared__ double ln[64], red[64];
  double s = (double)mu[sr * 64 + d] +
             (double)noise[bs * 64 + d] * exp((double)logsig[sr * 64 + d]);
  slots[bs * 64 + d] = s;
  red[d] = s;
  __syncthreads();
  for (int st = 32; st > 0; st >>= 1) {
    if (d < st) red[d] += red[d + st];
    __syncthreads();
  }
  double m = red[0] * (1.0 / 64.0);
  __syncthreads();
  double dv = s - m;
  red[d] = dv * dv;
  __syncthreads();
  for (int st = 32; st > 0; st >>= 1) {
    if (d < st) red[d] += red[d + st];
    __syncthreads();
  }
  double isd = 1.0 / sqrt(red[0] * (1.0 / 64.0) + 1e-5);
  __syncthreads();
  ln[d] = dv * isd;
  __syncthreads();
  double q = 0.0;
  for (int dd = 0; dd < 64; ++dd) q += ln[dd] * (double)wq[dd * 64 + d];
  qbuf[bs * 64 + d] = q * 0.125;
}

// ---------------------------------------------------------------------------
// Attention logits + softmax over s (+1e-8). One thread per (b,n).
// ---------------------------------------------------------------------------
__global__ __launch_bounds__(256) void attn_softmax(
    const float* __restrict__ kbuf, const double* __restrict__ qbuf,
    double* __restrict__ attw) {
  int idx = blockIdx.x * 256 + threadIdx.x;  // b*1024+n
  if (idx >= 32 * 1024) return;
  int b = idx >> 10;
  double l[7];
  for (int s = 0; s < 7; ++s) {
    double acc = 0.0;
    for (int d = 0; d < 64; ++d)
      acc += (double)kbuf[idx * 64 + d] * qbuf[(b * 7 + s) * 64 + d];
    l[s] = acc;
  }
  double mx = l[0];
  for (int s = 1; s < 7; ++s) mx = fmax(mx, l[s]);
  double sum = 0.0;
  for (int s = 0; s < 7; ++s) {
    l[s] = exp(l[s] - mx);
    sum += l[s];
  }
  double inv = 1.0 / sum;
  for (int s = 0; s < 7; ++s) attw[idx * 7 + s] = l[s] * inv + 1e-8;
}

// ---------------------------------------------------------------------------
// Weighted-mean updates. Block per (b,s), 64 threads (d).
// ---------------------------------------------------------------------------
__global__ __launch_bounds__(64) void attn_updates(
    const double* __restrict__ attw, const float* __restrict__ vbuf,
    double* __restrict__ upd) {
  int bs = blockIdx.x;
  int b = bs / 7, s = bs % 7;
  int d = threadIdx.x;
  __shared__ double red[64];
  double ps = 0.0;
  for (int n = d; n < 1024; n += 64) ps += attw[(b * 1024 + n) * 7 + s];
  red[d] = ps;
  __syncthreads();
  for (int st = 32; st > 0; st >>= 1) {
    if (d < st) red[d] += red[d + st];
    __syncthreads();
  }
  double asum = red[0];
  double acc = 0.0;
  for (int n = 0; n < 1024; ++n)
    acc += attw[(b * 1024 + n) * 7 + s] * (double)vbuf[(b * 1024 + n) * 64 + d];
  upd[bs * 64 + d] = acc / asum;
}

// ---------------------------------------------------------------------------
// GRU + residual MLP + next q. Block per (b,s), 64 threads.
// ---------------------------------------------------------------------------
__global__ __launch_bounds__(64) void slot_update(
    const double* __restrict__ upd, const float* __restrict__ gwi,
    const float* __restrict__ gwh, const float* __restrict__ gb,
    const float* __restrict__ w1, const float* __restrict__ b1,
    const float* __restrict__ w2, const float* __restrict__ b2,
    const float* __restrict__ wq, double* __restrict__ slots,
    double* __restrict__ qbuf) {
  int bs = blockIdx.x;
  int d = threadIdx.x;
  __shared__ double u[64], p[64], ln[64], h[128], red[64];
  u[d] = upd[bs * 64 + d];
  p[d] = slots[bs * 64 + d];
  __syncthreads();
  double giz = (double)gb[d], gir = (double)gb[64 + d], gin = (double)gb[128 + d];
  double ghz = 0.0, ghr = 0.0, ghn = 0.0;
  for (int dd = 0; dd < 64; ++dd) {
    giz += u[dd] * (double)gwi[dd * 192 + d];
    gir += u[dd] * (double)gwi[dd * 192 + 64 + d];
    gin += u[dd] * (double)gwi[dd * 192 + 128 + d];
    ghz += p[dd] * (double)gwh[dd * 192 + d];
    ghr += p[dd] * (double)gwh[dd * 192 + 64 + d];
    ghn += p[dd] * (double)gwh[dd * 192 + 128 + d];
  }
  double z = 1.0 / (1.0 + exp(-(giz + ghz)));
  double r = 1.0 / (1.0 + exp(-(gir + ghr)));
  double nn = tanh(gin + r * ghn);
  double s = (1.0 - z) * nn + z * p[d];
  red[d] = s;
  __syncthreads();
  for (int st = 32; st > 0; st >>= 1) {
    if (d < st) red[d] += red[d + st];
    __syncthreads();
  }
  double m = red[0] * (1.0 / 64.0);
  __syncthreads();
  double dv = s - m;
  red[d] = dv * dv;
  __syncthreads();
  for (int st = 32; st > 0; st >>= 1) {
    if (d < st) red[d] += red[d + st];
    __syncthreads();
  }
  double isd = 1.0 / sqrt(red[0] * (1.0 / 64.0) + 1e-5);
  __syncthreads();
  ln[d] = dv * isd;
  __syncthreads();
  double h0 = (double)b1[d], h1 = (double)b1[64 + d];
  for (int dd = 0; dd < 64; ++dd) {
    h0 += ln[dd] * (double)w1[dd * 128 + d];
    h1 += ln[dd] * (double)w1[dd * 128 + 64 + d];
  }
  h[d] = fmax(h0, 0.0);
  h[64 + d] = fmax(h1, 0.0);
  __syncthreads();
  double o = (double)b2[d];
  for (int e = 0; e < 128; ++e) o += h[e] * (double)w2[e * 64 + d];
  double s2 = s + o;
  slots[bs * 64 + d] = s2;
  red[d] = s2;
  __syncthreads();
  for (int st = 32; st > 0; st >>= 1) {
    if (d < st) red[d] += red[d + st];
    __syncthreads();
  }
  double m2 = red[0] * (1.0 / 64.0);
  __syncthreads();
  double dv2 = s2 - m2;
  red[d] = dv2 * dv2;
  __syncthreads();
  for (int st = 32; st > 0; st >>= 1) {
    if (d < st) red[d] += red[d + st];
    __syncthreads();
  }
  double isd2 = 1.0 / sqrt(red[0] * (1.0 / 64.0) + 1e-5);
  __syncthreads();
  ln[d] = dv2 * isd2;
  __syncthreads();
  double q = 0.0;
  for (int dd = 0; dd < 64; ++dd) q += ln[dd] * (double)wq[dd * 64 + d];
  qbuf[bs * 64 + d] = q * 0.125;
}

// ---------------------------------------------------------------------------
// Estimator scores. One thread per (b,s,a).
// ---------------------------------------------------------------------------
__global__ __launch_bounds__(256) void scores_naive(
    const double* __restrict__ slots, const float* __restrict__ we,
    const float* __restrict__ wd, double* __restrict__ sc) {
  int idx = blockIdx.x * 256 + threadIdx.x;  // bs*50 + a
  if (idx >= 224 * 50) return;
  int a = idx % 50, bs = idx / 50;
  double lat[32];
  for (int z = 0; z < 32; ++z) {
    double acc = 0.0;
    for (int dd = 0; dd < 64; ++dd)
      acc += slots[bs * 64 + dd] * (double)we[(a * 64 + dd) * 32 + z];
    lat[z] = acc;
  }
  double sum = 0.0;
  for (int dd = 0; dd < 64; ++dd) {
    double rec = 0.0;
    for (int z = 0; z < 32; ++z) rec += lat[z] * (double)wd[(a * 32 + z) * 64 + dd];
    double df = rec - slots[bs * 64 + dd];
    sum += df * df;
  }
  sc[idx] = -sum;
}

// ---------------------------------------------------------------------------
// Top-3 per (b,s), serial, lowest-index tie-break. One thread per bs.
// ---------------------------------------------------------------------------
__global__ __launch_bounds__(256) void topk_naive(const double* __restrict__ sc,
                                                  int* __restrict__ topk) {
  int bs = blockIdx.x * 256 + threadIdx.x;
  if (bs >= 224) return;
  int chosen[3];
  for (int r = 0; r < 3; ++r) {
    double best = -1e300;
    int bi = -1;
    for (int a = 0; a < 50; ++a) {
      bool skip = false;
      for (int rr = 0; rr < r; ++rr)
        if (chosen[rr] == a) skip = true;
      if (skip) continue;
      double v = sc[bs * 50 + a];
      if (v > best) {
        best = v;
        bi = a;
      }
    }
    chosen[r] = bi;
    topk[bs * 3 + r] = bi;
  }
}

// ---------------------------------------------------------------------------
// Expert MLP, one block per token (672 blocks, 256 threads), f64 LDS h.
// ---------------------------------------------------------------------------
__global__ __launch_bounds__(256) void expert_naive(
    const int* __restrict__ topk, const double* __restrict__ slots,
    const float* __restrict__ win, const float* __restrict__ bin,
    const float* __restrict__ wblk, const float* __restrict__ bblk,
    const float* __restrict__ wout, const float* __restrict__ bout,
    float* __restrict__ outp) {
  int ti = blockIdx.x;  // (b*7+s)*3 + kk
  int a = topk[ti];
  int bs = ti / 3;
  int t = threadIdx.x;
  __shared__ double tok[64], ha[256], hb[256];
  if (t < 64) tok[t] = slots[bs * 64 + t];
  __syncthreads();
  double acc = (double)bin[a * 256 + t];
  for (int dd = 0; dd < 64; ++dd)
    acc += tok[dd] * (double)win[(a * 64 + dd) * 256 + t];
  ha[t] = fmax(acc, 0.0);
  __syncthreads();
  double* cur = ha;
  double* nxt = hb;
  for (int i = 0; i < 3; ++i) {
    double a2 = cur[t] + (double)bblk[(a * 3 + i) * 256 + t];
    for (int hh = 0; hh < 256; ++hh)
      a2 += cur[hh] * (double)wblk[((a * 3 + i) * 256 + hh) * 256 + t];
    nxt[t] = fmax(a2, 0.0);
    __syncthreads();
    double* tmp = cur;
    cur = nxt;
    nxt = tmp;
  }
  if (t < 128) {
    double a3 = (double)bout[a * 128 + t];
    for (int hh = 0; hh < 256; ++hh)
      a3 += cur[hh] * (double)wout[(a * 256 + hh) * 128 + t];
    outp[ti * 128 + t] = (float)a3;
  }
}

// ---------------------------------------------------------------------------
extern "C" void kernel_launch(void* const* d_in, const int* in_sizes, int n_in,
                              void* d_out, int out_size, void* d_ws,
                              size_t ws_size, hipStream_t stream) {
  (void)in_sizes; (void)n_in; (void)out_size; (void)ws_size;
  const float* images = (const float*)d_in[0];
  const float* noise = (const float*)d_in[1];
  const float* enc_w0 = (const float*)d_in[2];
  const float* enc_b0 = (const float*)d_in[3];
  const float* enc_w = (const float*)d_in[4];
  const float* enc_b = (const float*)d_in[5];
  const float* enc_wo = (const float*)d_in[6];
  const float* enc_bo = (const float*)d_in[7];
  const float* wk = (const float*)d_in[8];
  const float* wv = (const float*)d_in[9];
  const float* wq = (const float*)d_in[10];
  const float* gru_wi = (const float*)d_in[11];
  const float* gru_wh = (const float*)d_in[12];
  const float* gru_b = (const float*)d_in[13];
  const float* mlp_w1 = (const float*)d_in[14];
  const float* mlp_b1 = (const float*)d_in[15];
  const float* mlp_w2 = (const float*)d_in[16];
  const float* mlp_b2 = (const float*)d_in[17];
  const float* mu = (const float*)d_in[18];
  const float* logsig = (const float*)d_in[19];
  const float* est_we = (const float*)d_in[20];
  const float* est_wd = (const float*)d_in[21];
  const float* ag_win = (const float*)d_in[22];
  const float* ag_bin = (const float*)d_in[23];
  const float* ag_wblk = (const float*)d_in[24];
  const float* ag_bblk = (const float*)d_in[25];
  const float* ag_wout = (const float*)d_in[26];
  const float* ag_bout = (const float*)d_in[27];

  // Workspace layout — byte-identical to the passing round-5 layout (~27.5MB)
  double* dws = (double*)d_ws;
  double* slots = dws;                  // 14336
  double* qbuf = slots + 14336;         // 14336
  double* upd = qbuf + 14336;           // 14336
  double* attw = upd + 14336;           // 229376
  double* sc = attw + 229376;           // 11200
  int* topk = (int*)(sc + 11200);       // 672 (pad to 1024)
  float* xA = (float*)(topk + 1024);    // 2097152 floats
  float* xB = xA + 2097152;             // 2097152
  float* vbuf = xB + 2097152;           // 2097152

  conv3x3_kernel<3, true><<<256, 256, 0, stream>>>(images, enc_w0, enc_b0, xA, 64, 1);
  conv3x3_kernel<64, true><<<256, 256, 0, stream>>>(xA, enc_w, enc_b, xB, 64, 1);
  conv3x3_kernel<64, true><<<256, 256, 0, stream>>>(xB, enc_w + 36864, enc_b + 64, xA, 64, 1);
  conv3x3_kernel<64, true><<<256, 256, 0, stream>>>(xA, enc_w + 73728, enc_b + 128, xB, 64, 1);
  // fused conv5 + LN + K/V: reads xB, writes k->xA, v->vbuf
  conv5_ln_kv_fused<<<2048, 256, 0, stream>>>(xB, enc_wo, enc_bo, wk, wv, xA, vbuf);
  slot_init<<<224, 64, 0, stream>>>(mu, logsig, noise, wq, slots, qbuf);
  for (int it = 0; it < 3; ++it) {
    attn_softmax<<<128, 256, 0, stream>>>(xA, qbuf, attw);
    attn_updates<<<224, 64, 0, stream>>>(attw, vbuf, upd);
    slot_update<<<224, 64, 0, stream>>>(upd, gru_wi, gru_wh, gru_b, mlp_w1,
                                        mlp_b1, mlp_w2, mlp_b2, wq, slots, qbuf);
  }
  scores_naive<<<44, 256, 0, stream>>>(slots, est_we, est_wd, sc);
  topk_naive<<<1, 256, 0, stream>>>(sc, topk);
  expert_naive<<<672, 256, 0, stream>>>(topk, slots, ag_win, ag_bin, ag_wblk,
                                        ag_bblk, ag_wout, ag_bout,
                                        (float*)d_out);
}

// Round 9
// 1755.048 us; speedup vs baseline: 11.2458x; 1.2334x over previous
//
#include <hip/hip_runtime.h>
#include <hip/hip_bf16.h>
#include <math.h>

#define DEV __device__ __forceinline__

DEV double wred_sumd(double v) {
#pragma unroll
  for (int m = 1; m < 64; m <<= 1) v += __shfl_xor(v, m, 64);
  return v;
}

// ---------------------------------------------------------------------------
// Tiled 3x3 SAME conv, NCHW, stride 1. f32 storage + f32 accumulation.
// Block = 256 thr covers (b, 4 h-rows, 64 co). Thread tile: 8 co x 4 w.
// LDS: s_in 13.4KB + s_w 36.9KB = 50.3KB (< 64KB).
// ---------------------------------------------------------------------------
template <int CIN, bool RELU>
__global__ __launch_bounds__(256) void conv3x3_kernel(
    const float* __restrict__ in, const float* __restrict__ wgt,
    const float* __restrict__ bias, float* __restrict__ out,
    int cout_total, int cb_count) {
  constexpr int CHUNK = (CIN < 16) ? CIN : 16;
  __shared__ float s_in[6 * CHUNK * 35];
  __shared__ float s_w[CHUNK * 9 * 64];
  int bx = blockIdx.x;
  int cb = bx % cb_count;
  bx /= cb_count;
  int hb = bx & 7;
  int b = bx >> 3;
  int co_base = cb * 64;
  int t = threadIdx.x;
  int w_g = t & 7, co_g = (t >> 3) & 7, h_l = t >> 6;
  int h0 = hb * 4;
  int w0 = w_g * 4;
  float acc[8][4];
#pragma unroll
  for (int j = 0; j < 8; ++j)
#pragma unroll
    for (int ww = 0; ww < 4; ++ww) acc[j][ww] = 0.f;

  for (int cc = 0; cc < CIN; cc += CHUNK) {
    __syncthreads();
    for (int i = t; i < 6 * CHUNK * 32; i += 256) {
      int r = i / (CHUNK * 32);
      int c = (i >> 5) % CHUNK;
      int w = i & 31;
      int gh = h0 - 1 + r;
      float v = 0.f;
      if (gh >= 0 && gh < 32) v = in[((b * CIN + cc + c) * 32 + gh) * 32 + w];
      s_in[(r * CHUNK + c) * 35 + w + 1] = v;
    }
    for (int i = t; i < 6 * CHUNK; i += 256) {
      s_in[i * 35] = 0.f;
      s_in[i * 35 + 33] = 0.f;
    }
    for (int i = t; i < CHUNK * 9 * 64; i += 256) {
      int co = i / (CHUNK * 9);
      int rem = i % (CHUNK * 9);
      s_w[rem * 64 + co] = wgt[((co_base + co) * CIN + cc) * 9 + rem];
    }
    __syncthreads();
    for (int c = 0; c < CHUNK; ++c) {
#pragma unroll
      for (int kh = 0; kh < 3; ++kh) {
        const float* ip = &s_in[((h_l + kh) * CHUNK + c) * 35 + w0];
        float ivs[6];
#pragma unroll
        for (int j = 0; j < 6; ++j) ivs[j] = ip[j];
        const float* wp = &s_w[(c * 9 + kh * 3) * 64 + co_g * 8];
#pragma unroll
        for (int kw = 0; kw < 3; ++kw) {
          float4 wa = *(const float4*)(wp + kw * 64);
          float4 wb = *(const float4*)(wp + kw * 64 + 4);
          float wr[8] = {wa.x, wa.y, wa.z, wa.w, wb.x, wb.y, wb.z, wb.w};
#pragma unroll
          for (int j = 0; j < 8; ++j)
#pragma unroll
            for (int ww = 0; ww < 4; ++ww)
              acc[j][ww] = fmaf(ivs[kw + ww], wr[j], acc[j][ww]);
        }
      }
    }
  }
  int h = h0 + h_l;
#pragma unroll
  for (int j = 0; j < 8; ++j) {
    int co = co_base + co_g * 8 + j;
    float bv = bias[co];
    float4 o;
    o.x = acc[j][0] + bv;
    o.y = acc[j][1] + bv;
    o.z = acc[j][2] + bv;
    o.w = acc[j][3] + bv;
    if (RELU) {
      o.x = fmaxf(o.x, 0.f);
      o.y = fmaxf(o.y, 0.f);
      o.z = fmaxf(o.z, 0.f);
      o.w = fmaxf(o.w, 0.f);
    }
    *(float4*)(&out[((b * cout_total + co) * 32 + h) * 32 + w0]) = o;
  }
}

// ---------------------------------------------------------------------------
// Fused conv5 (64->256) + LayerNorm(256) + K/V projection. All f32.
// Block = (b, 16 pixels); 256 thr = 16 px x 16 co-groups.
// LDS: s_w 18.4KB + s_xn 16.4KB + misc ~1.7KB = ~36.6KB -> 4 blocks/CU.
// ---------------------------------------------------------------------------
__global__ __launch_bounds__(256) void conv5_ln_kv_fused(
    const float* __restrict__ in,    // (B,64,32,32)
    const float* __restrict__ wgt,   // (256,64,3,3)
    const float* __restrict__ bias,  // (256)
    const float* __restrict__ wk, const float* __restrict__ wv,
    float* __restrict__ kout, float* __restrict__ vout) {
  int bp = blockIdx.x;            // b*64 + pt
  int b = bp >> 6, pt = bp & 63;  // 64 pixel-tiles of 16
  int h = pt >> 1, w0 = (pt & 1) * 16;
  int t = threadIdx.x;
  int px = t & 15, cg = t >> 4;  // co = cg*16 + j

  __shared__ float s_w[2 * 9 * 256];
  __shared__ float s_in[2][3][20];
  __shared__ float s_red[16][17];
  __shared__ float s_m[16], s_isd[16];
  __shared__ float s_xn[16][257];  // stride 257 -> conflict-minimal

  float acc[16];
#pragma unroll
  for (int j = 0; j < 16; ++j) acc[j] = 0.f;

  for (int cc = 0; cc < 64; cc += 2) {
    __syncthreads();
    for (int i = t; i < 2 * 9 * 256; i += 256) {
      int co = i & 255;
      int rem = i >> 8;
      int c = rem / 9, k = rem % 9;
      s_w[(c * 9 + k) * 256 + co] = wgt[(co * 64 + cc + c) * 9 + k];
    }
    for (int i = t; i < 2 * 3 * 18; i += 256) {
      int c = i / 54;
      int r = (i / 18) % 3;
      int cw = i % 18;
      int gh = h + r - 1;
      int gw = w0 + cw - 1;
      float v = 0.f;
      if (gh >= 0 && gh < 32 && gw >= 0 && gw < 32)
        v = in[((b * 64 + c + cc) * 32 + gh) * 32 + gw];
      s_in[c][r][cw] = v;
    }
    __syncthreads();
#pragma unroll
    for (int c = 0; c < 2; ++c) {
#pragma unroll
      for (int kh = 0; kh < 3; ++kh) {
        float iv[3];
#pragma unroll
        for (int kw = 0; kw < 3; ++kw) iv[kw] = s_in[c][kh][px + kw];
        const float* wp = &s_w[(c * 9 + kh * 3) * 256 + cg * 16];
#pragma unroll
        for (int kw = 0; kw < 3; ++kw) {
#pragma unroll
          for (int j = 0; j < 16; ++j)
            acc[j] = fmaf(iv[kw], wp[kw * 256 + j], acc[j]);
        }
      }
    }
  }
  // bias + LayerNorm over 256 channels of pixel px
#pragma unroll
  for (int j = 0; j < 16; ++j) acc[j] += bias[cg * 16 + j];
  float psum = 0.f;
#pragma unroll
  for (int j = 0; j < 16; ++j) psum += acc[j];
  s_red[px][cg] = psum;
  __syncthreads();
  if (t < 16) {
    float m = 0.f;
    for (int g = 0; g < 16; ++g) m += s_red[t][g];
    s_m[t] = m * (1.f / 256.f);
  }
  __syncthreads();
  float m = s_m[px];
  float vp = 0.f;
#pragma unroll
  for (int j = 0; j < 16; ++j) {
    float dv = acc[j] - m;
    vp += dv * dv;
  }
  s_red[px][cg] = vp;
  __syncthreads();
  if (t < 16) {
    float v = 0.f;
    for (int g = 0; g < 16; ++g) v += s_red[t][g];
    s_isd[t] = 1.f / sqrtf(v * (1.f / 256.f) + 1e-5f);
  }
  __syncthreads();
  float isd = s_isd[px];
#pragma unroll
  for (int j = 0; j < 16; ++j) s_xn[px][cg * 16 + j] = (acc[j] - m) * isd;
  __syncthreads();
  // K/V projection: thread -> (px, cg); cg 0..7 -> k cols, 8..15 -> v
  const float* wb = (cg < 8) ? wk : wv;
  int d0 = (cg & 7) * 8;
  float a2[8];
#pragma unroll
  for (int j = 0; j < 8; ++j) a2[j] = 0.f;
  for (int c = 0; c < 256; ++c) {
    float xv = s_xn[px][c];
    const float* wr = &wb[c * 64 + d0];
#pragma unroll
    for (int j = 0; j < 8; ++j) a2[j] = fmaf(xv, wr[j], a2[j]);
  }
  int p = h * 32 + w0 + px;
  float* ob = (cg < 8) ? kout : vout;
#pragma unroll
  for (int j = 0; j < 8; ++j) ob[(b * 1024 + p) * 64 + d0 + j] = a2[j];
}

// ---------------------------------------------------------------------------
// Slot init + first q. Block per (b,s) = 224 blocks, 64 threads. (unchanged)
// ---------------------------------------------------------------------------
__global__ __launch_bounds__(64) void slot_init(
    const float* __restrict__ mu, const float* __restrict__ logsig,
    const float* __restrict__ noise, const float* __restrict__ wq,
    double* __restrict__ slots, double* __restrict__ qbuf) {
  int bs = blockIdx.x;
  int d = threadIdx.x;
  int sr = bs % 7;
  __shared__ double ln[64], red[64];
  double s = (double)mu[sr * 64 + d] +
             (double)noise[bs * 64 + d] * exp((double)logsig[sr * 64 + d]);
  slots[bs * 64 + d] = s;
  red[d] = s;
  __syncthreads();
  for (int st = 32; st > 0; st >>= 1) {
    if (d < st) red[d] += red[d + st];
    __syncthreads();
  }
  double m = red[0] * (1.0 / 64.0);
  __syncthreads();
  double dv = s - m;
  red[d] = dv * dv;
  __syncthreads();
  for (int st = 32; st > 0; st >>= 1) {
    if (d < st) red[d] += red[d + st];
    __syncthreads();
  }
  double isd = 1.0 / sqrt(red[0] * (1.0 / 64.0) + 1e-5);
  __syncthreads();
  ln[d] = dv * isd;
  __syncthreads();
  double q = 0.0;
  for (int dd = 0; dd < 64; ++dd) q += ln[dd] * (double)wq[dd * 64 + d];
  qbuf[bs * 64 + d] = q * 0.125;
}

// ---------------------------------------------------------------------------
// Attention logits + softmax over s (+1e-8). One thread per (b,n).
// Writes TRANSPOSED attw layout: attw[(b*7+s)*1024 + n] for coalesced reads.
// ---------------------------------------------------------------------------
__global__ __launch_bounds__(256) void attn_softmax(
    const float* __restrict__ kbuf, const double* __restrict__ qbuf,
    double* __restrict__ attw) {
  int idx = blockIdx.x * 256 + threadIdx.x;  // b*1024+n
  if (idx >= 32 * 1024) return;
  int b = idx >> 10;
  int n = idx & 1023;
  double l[7];
  for (int s = 0; s < 7; ++s) {
    double acc = 0.0;
    for (int d = 0; d < 64; ++d)
      acc += (double)kbuf[idx * 64 + d] * qbuf[(b * 7 + s) * 64 + d];
    l[s] = acc;
  }
  double mx = l[0];
  for (int s = 1; s < 7; ++s) mx = fmax(mx, l[s]);
  double sum = 0.0;
  for (int s = 0; s < 7; ++s) {
    l[s] = exp(l[s] - mx);
    sum += l[s];
  }
  double inv = 1.0 / sum;
  for (int s = 0; s < 7; ++s)
    attw[(size_t)(b * 7 + s) * 1024 + n] = l[s] * inv + 1e-8;
}

// ---------------------------------------------------------------------------
// FUSED weighted-mean update + GRU + residual MLP + next q.
// Block per (b,s), 256 threads. Phase 1: 4-way parallel (n-quarters) upd/asum.
// Phase 2: wave 0 only (shuffle reductions, wave-coherent LDS).
// ---------------------------------------------------------------------------
__global__ __launch_bounds__(256) void attn_update_slot(
    const double* __restrict__ attw, const float* __restrict__ vbuf,
    const float* __restrict__ gwi, const float* __restrict__ gwh,
    const float* __restrict__ gb, const float* __restrict__ w1,
    const float* __restrict__ b1, const float* __restrict__ w2,
    const float* __restrict__ b2, const float* __restrict__ wq,
    double* __restrict__ slots, double* __restrict__ qbuf) {
  int bs = blockIdx.x;
  int b = bs / 7;
  int t = threadIdx.x;
  int d = t & 63, q = t >> 6;
  __shared__ double s_aw[1024];
  __shared__ double part[4][64];
  __shared__ double red256[256];
  __shared__ double s_u[64], s_p[64], s_ln[64], s_h[128];
  for (int i = t; i < 1024; i += 256) s_aw[i] = attw[(size_t)bs * 1024 + i];
  __syncthreads();
  // asum partials (each thread sums 4 entries of its n-quarter)
  double ps = 0.0;
#pragma unroll
  for (int k = 0; k < 4; ++k) ps += s_aw[q * 256 + k * 64 + d];
  red256[t] = ps;
  // upd partials: sum over this quarter's 256 n of a[n]*v[n][d]
  double acc = 0.0;
  const float* vb = vbuf + ((size_t)(b * 1024 + q * 256)) * 64 + d;
  for (int n = 0; n < 256; ++n)
    acc += s_aw[q * 256 + n] * (double)vb[(size_t)n * 64];
  part[q][d] = acc;
  __syncthreads();
  for (int st = 128; st > 0; st >>= 1) {
    if (t < st) red256[t] += red256[t + st];
    __syncthreads();
  }
  double asum = red256[0];
  if (t < 64) {
    double u = ((part[0][d] + part[1][d]) + part[2][d]) + part[3][d];
    s_u[d] = u / asum;
    s_p[d] = slots[bs * 64 + d];
  }
  __syncthreads();
  if (t >= 64) return;
  // ---- wave 0 only: GRU + LN + MLP + LN + q ----
  double giz = (double)gb[d], gir = (double)gb[64 + d], gin = (double)gb[128 + d];
  double ghz = 0.0, ghr = 0.0, ghn = 0.0;
  for (int dd = 0; dd < 64; ++dd) {
    double uu = s_u[dd], pp = s_p[dd];
    giz += uu * (double)gwi[dd * 192 + d];
    gir += uu * (double)gwi[dd * 192 + 64 + d];
    gin += uu * (double)gwi[dd * 192 + 128 + d];
    ghz += pp * (double)gwh[dd * 192 + d];
    ghr += pp * (double)gwh[dd * 192 + 64 + d];
    ghn += pp * (double)gwh[dd * 192 + 128 + d];
  }
  double z = 1.0 / (1.0 + exp(-(giz + ghz)));
  double r = 1.0 / (1.0 + exp(-(gir + ghr)));
  double nn = tanh(gin + r * ghn);
  double sv = (1.0 - z) * nn + z * s_p[d];
  double m = wred_sumd(sv) * (1.0 / 64.0);
  double dv = sv - m;
  double var = wred_sumd(dv * dv) * (1.0 / 64.0);
  s_ln[d] = dv / sqrt(var + 1e-5);
  double h0 = (double)b1[d], h1 = (double)b1[64 + d];
  for (int dd = 0; dd < 64; ++dd) {
    double lv = s_ln[dd];
    h0 += lv * (double)w1[dd * 128 + d];
    h1 += lv * (double)w1[dd * 128 + 64 + d];
  }
  s_h[d] = fmax(h0, 0.0);
  s_h[64 + d] = fmax(h1, 0.0);
  double o = (double)b2[d];
  for (int e = 0; e < 128; ++e) o += s_h[e] * (double)w2[e * 64 + d];
  double s2 = sv + o;
  slots[bs * 64 + d] = s2;
  double m2 = wred_sumd(s2) * (1.0 / 64.0);
  double dv2 = s2 - m2;
  double var2 = wred_sumd(dv2 * dv2) * (1.0 / 64.0);
  s_ln[d] = dv2 / sqrt(var2 + 1e-5);
  double qv = 0.0;
  for (int dd = 0; dd < 64; ++dd) qv += s_ln[dd] * (double)wq[dd * 64 + d];
  qbuf[bs * 64 + d] = qv * 0.125;
}

// ---------------------------------------------------------------------------
// Estimator scores. One thread per (b,s,a). (unchanged)
// ---------------------------------------------------------------------------
__global__ __launch_bounds__(256) void scores_naive(
    const double* __restrict__ slots, const float* __restrict__ we,
    const float* __restrict__ wd, double* __restrict__ sc) {
  int idx = blockIdx.x * 256 + threadIdx.x;  // bs*50 + a
  if (idx >= 224 * 50) return;
  int a = idx % 50, bs = idx / 50;
  double lat[32];
  for (int z = 0; z < 32; ++z) {
    double acc = 0.0;
    for (int dd = 0; dd < 64; ++dd)
      acc += slots[bs * 64 + dd] * (double)we[(a * 64 + dd) * 32 + z];
    lat[z] = acc;
  }
  double sum = 0.0;
  for (int dd = 0; dd < 64; ++dd) {
    double rec = 0.0;
    for (int z = 0; z < 32; ++z) rec += lat[z] * (double)wd[(a * 32 + z) * 64 + dd];
    double df = rec - slots[bs * 64 + dd];
    sum += df * df;
  }
  sc[idx] = -sum;
}

// ---------------------------------------------------------------------------
// Top-3 per (b,s), serial, lowest-index tie-break. (unchanged)
// ---------------------------------------------------------------------------
__global__ __launch_bounds__(256) void topk_naive(const double* __restrict__ sc,
                                                  int* __restrict__ topk) {
  int bs = blockIdx.x * 256 + threadIdx.x;
  if (bs >= 224) return;
  int chosen[3];
  for (int r = 0; r < 3; ++r) {
    double best = -1e300;
    int bi = -1;
    for (int a = 0; a < 50; ++a) {
      bool skip = false;
      for (int rr = 0; rr < r; ++rr)
        if (chosen[rr] == a) skip = true;
      if (skip) continue;
      double v = sc[bs * 50 + a];
      if (v > best) {
        best = v;
        bi = a;
      }
    }
    chosen[r] = bi;
    topk[bs * 3 + r] = bi;
  }
}

// ---------------------------------------------------------------------------
// Expert MLP, one block per token (672 blocks, 256 threads). (unchanged)
// ---------------------------------------------------------------------------
__global__ __launch_bounds__(256) void expert_naive(
    const int* __restrict__ topk, const double* __restrict__ slots,
    const float* __restrict__ win, const float* __restrict__ bin,
    const float* __restrict__ wblk, const float* __restrict__ bblk,
    const float* __restrict__ wout, const float* __restrict__ bout,
    float* __restrict__ outp) {
  int ti = blockIdx.x;  // (b*7+s)*3 + kk
  int a = topk[ti];
  int bs = ti / 3;
  int t = threadIdx.x;
  __shared__ double tok[64], ha[256], hb[256];
  if (t < 64) tok[t] = slots[bs * 64 + t];
  __syncthreads();
  double acc = (double)bin[a * 256 + t];
  for (int dd = 0; dd < 64; ++dd)
    acc += tok[dd] * (double)win[(a * 64 + dd) * 256 + t];
  ha[t] = fmax(acc, 0.0);
  __syncthreads();
  double* cur = ha;
  double* nxt = hb;
  for (int i = 0; i < 3; ++i) {
    double a2 = cur[t] + (double)bblk[(a * 3 + i) * 256 + t];
    for (int hh = 0; hh < 256; ++hh)
      a2 += cur[hh] * (double)wblk[((a * 3 + i) * 256 + hh) * 256 + t];
    nxt[t] = fmax(a2, 0.0);
    __syncthreads();
    double* tmp = cur;
    cur = nxt;
    nxt = tmp;
  }
  if (t < 128) {
    double a3 = (double)bout[a * 128 + t];
    for (int hh = 0; hh < 256; ++hh)
      a3 += cur[hh] * (double)wout[(a * 256 + hh) * 128 + t];
    outp[ti * 128 + t] = (float)a3;
  }
}

// ---------------------------------------------------------------------------
extern "C" void kernel_launch(void* const* d_in, const int* in_sizes, int n_in,
                              void* d_out, int out_size, void* d_ws,
                              size_t ws_size, hipStream_t stream) {
  (void)in_sizes; (void)n_in; (void)out_size; (void)ws_size;
  const float* images = (const float*)d_in[0];
  const float* noise = (const float*)d_in[1];
  const float* enc_w0 = (const float*)d_in[2];
  const float* enc_b0 = (const float*)d_in[3];
  const float* enc_w = (const float*)d_in[4];
  const float* enc_b = (const float*)d_in[5];
  const float* enc_wo = (const float*)d_in[6];
  const float* enc_bo = (const float*)d_in[7];
  const float* wk = (const float*)d_in[8];
  const float* wv = (const float*)d_in[9];
  const float* wq = (const float*)d_in[10];
  const float* gru_wi = (const float*)d_in[11];
  const float* gru_wh = (const float*)d_in[12];
  const float* gru_b = (const float*)d_in[13];
  const float* mlp_w1 = (const float*)d_in[14];
  const float* mlp_b1 = (const float*)d_in[15];
  const float* mlp_w2 = (const float*)d_in[16];
  const float* mlp_b2 = (const float*)d_in[17];
  const float* mu = (const float*)d_in[18];
  const float* logsig = (const float*)d_in[19];
  const float* est_we = (const float*)d_in[20];
  const float* est_wd = (const float*)d_in[21];
  const float* ag_win = (const float*)d_in[22];
  const float* ag_bin = (const float*)d_in[23];
  const float* ag_wblk = (const float*)d_in[24];
  const float* ag_bblk = (const float*)d_in[25];
  const float* ag_wout = (const float*)d_in[26];
  const float* ag_bout = (const float*)d_in[27];

  // Workspace layout — byte-identical to the passing round-5/8 layout
  double* dws = (double*)d_ws;
  double* slots = dws;                  // 14336
  double* qbuf = slots + 14336;         // 14336
  double* upd = qbuf + 14336;           // 14336 (unused now, kept for layout)
  double* attw = upd + 14336;           // 229376 (= 224*1024, [bs][n])
  double* sc = attw + 229376;           // 11200
  int* topk = (int*)(sc + 11200);       // 672 (pad to 1024)
  float* xA = (float*)(topk + 1024);    // 2097152 floats
  float* xB = xA + 2097152;             // 2097152
  float* vbuf = xB + 2097152;           // 2097152

  conv3x3_kernel<3, true><<<256, 256, 0, stream>>>(images, enc_w0, enc_b0, xA, 64, 1);
  conv3x3_kernel<64, true><<<256, 256, 0, stream>>>(xA, enc_w, enc_b, xB, 64, 1);
  conv3x3_kernel<64, true><<<256, 256, 0, stream>>>(xB, enc_w + 36864, enc_b + 64, xA, 64, 1);
  conv3x3_kernel<64, true><<<256, 256, 0, stream>>>(xA, enc_w + 73728, enc_b + 128, xB, 64, 1);
  // fused conv5 + LN + K/V: reads xB, writes k->xA, v->vbuf
  conv5_ln_kv_fused<<<2048, 256, 0, stream>>>(xB, enc_wo, enc_bo, wk, wv, xA, vbuf);
  slot_init<<<224, 64, 0, stream>>>(mu, logsig, noise, wq, slots, qbuf);
  for (int it = 0; it < 3; ++it) {
    attn_softmax<<<128, 256, 0, stream>>>(xA, qbuf, attw);
    attn_update_slot<<<224, 256, 0, stream>>>(attw, vbuf, gru_wi, gru_wh,
                                              gru_b, mlp_w1, mlp_b1, mlp_w2,
                                              mlp_b2, wq, slots, qbuf);
  }
  scores_naive<<<44, 256, 0, stream>>>(slots, est_we, est_wd, sc);
  topk_naive<<<1, 256, 0, stream>>>(sc, topk);
  expert_naive<<<672, 256, 0, stream>>>(topk, slots, ag_win, ag_bin, ag_wblk,
                                        ag_bblk, ag_wout, ag_bout,
                                        (float*)d_out);
}

// Round 11
// 1477.689 us; speedup vs baseline: 13.3566x; 1.1877x over previous
//
#include <hip/hip_runtime.h>
#include <hip/hip_bf16.h>
#include <math.h>

#define DEV __device__ __forceinline__

DEV double wred_sumd(double v) {
#pragma unroll
  for (int m = 1; m < 64; m <<= 1) v += __shfl_xor(v, m, 64);
  return v;
}

// ---------------------------------------------------------------------------
// Tiled 3x3 SAME conv, NCHW, stride 1. f32 storage + f32 accumulation.
// Block = 256 thr covers (b, 4 h-rows, 64 co). Thread tile: 8 co x 4 w.
// (Weight staging here is already coalesced: contiguous 144-float runs.)
// ---------------------------------------------------------------------------
template <int CIN, bool RELU>
__global__ __launch_bounds__(256) void conv3x3_kernel(
    const float* __restrict__ in, const float* __restrict__ wgt,
    const float* __restrict__ bias, float* __restrict__ out,
    int cout_total, int cb_count) {
  constexpr int CHUNK = (CIN < 16) ? CIN : 16;
  __shared__ float s_in[6 * CHUNK * 35];
  __shared__ float s_w[CHUNK * 9 * 64];
  int bx = blockIdx.x;
  int cb = bx % cb_count;
  bx /= cb_count;
  int hb = bx & 7;
  int b = bx >> 3;
  int co_base = cb * 64;
  int t = threadIdx.x;
  int w_g = t & 7, co_g = (t >> 3) & 7, h_l = t >> 6;
  int h0 = hb * 4;
  int w0 = w_g * 4;
  float acc[8][4];
#pragma unroll
  for (int j = 0; j < 8; ++j)
#pragma unroll
    for (int ww = 0; ww < 4; ++ww) acc[j][ww] = 0.f;

  for (int cc = 0; cc < CIN; cc += CHUNK) {
    __syncthreads();
    for (int i = t; i < 6 * CHUNK * 32; i += 256) {
      int r = i / (CHUNK * 32);
      int c = (i >> 5) % CHUNK;
      int w = i & 31;
      int gh = h0 - 1 + r;
      float v = 0.f;
      if (gh >= 0 && gh < 32) v = in[((b * CIN + cc + c) * 32 + gh) * 32 + w];
      s_in[(r * CHUNK + c) * 35 + w + 1] = v;
    }
    for (int i = t; i < 6 * CHUNK; i += 256) {
      s_in[i * 35] = 0.f;
      s_in[i * 35 + 33] = 0.f;
    }
    for (int i = t; i < CHUNK * 9 * 64; i += 256) {
      int co = i / (CHUNK * 9);
      int rem = i % (CHUNK * 9);
      s_w[rem * 64 + co] = wgt[((co_base + co) * CIN + cc) * 9 + rem];
    }
    __syncthreads();
    for (int c = 0; c < CHUNK; ++c) {
#pragma unroll
      for (int kh = 0; kh < 3; ++kh) {
        const float* ip = &s_in[((h_l + kh) * CHUNK + c) * 35 + w0];
        float ivs[6];
#pragma unroll
        for (int j = 0; j < 6; ++j) ivs[j] = ip[j];
        const float* wp = &s_w[(c * 9 + kh * 3) * 64 + co_g * 8];
#pragma unroll
        for (int kw = 0; kw < 3; ++kw) {
          float4 wa = *(const float4*)(wp + kw * 64);
          float4 wb = *(const float4*)(wp + kw * 64 + 4);
          float wr[8] = {wa.x, wa.y, wa.z, wa.w, wb.x, wb.y, wb.z, wb.w};
#pragma unroll
          for (int j = 0; j < 8; ++j)
#pragma unroll
            for (int ww = 0; ww < 4; ++ww)
              acc[j][ww] = fmaf(ivs[kw + ww], wr[j], acc[j][ww]);
        }
      }
    }
  }
  int h = h0 + h_l;
#pragma unroll
  for (int j = 0; j < 8; ++j) {
    int co = co_base + co_g * 8 + j;
    float bv = bias[co];
    float4 o;
    o.x = acc[j][0] + bv;
    o.y = acc[j][1] + bv;
    o.z = acc[j][2] + bv;
    o.w = acc[j][3] + bv;
    if (RELU) {
      o.x = fmaxf(o.x, 0.f);
      o.y = fmaxf(o.y, 0.f);
      o.z = fmaxf(o.z, 0.f);
      o.w = fmaxf(o.w, 0.f);
    }
    *(float4*)(&out[((b * cout_total + co) * 32 + h) * 32 + w0]) = o;
  }
}

// ---------------------------------------------------------------------------
// Fused conv5 (64->256) + LayerNorm(256) + K/V projection. All f32.
// Block = (b, 16 pixels); 256 thr = 16 px x 16 co-groups.
// FIXED: weight staging now globally COALESCED (contiguous 18-float runs per
// co) into padded LDS s_w[rem*257+co] (conflict-free writes, b128 reads).
// LDS: s_w 18.5KB + s_xn 16.4KB + misc ~1.8KB = ~36.7KB -> 4 blocks/CU.
// ---------------------------------------------------------------------------
__global__ __launch_bounds__(256) void conv5_ln_kv_fused(
    const float* __restrict__ in,    // (B,64,32,32)
    const float* __restrict__ wgt,   // (256,64,3,3)
    const float* __restrict__ bias,  // (256)
    const float* __restrict__ wk, const float* __restrict__ wv,
    float* __restrict__ kout, float* __restrict__ vout) {
  int bp = blockIdx.x;            // b*64 + pt
  int b = bp >> 6, pt = bp & 63;  // 64 pixel-tiles of 16
  int h = pt >> 1, w0 = (pt & 1) * 16;
  int t = threadIdx.x;
  int px = t & 15, cg = t >> 4;  // co = cg*16 + j

  __shared__ float s_w[18 * 257];  // [rem][co], rem = c*9 + kh*3 + kw
  __shared__ float s_in[2][3][20];
  __shared__ float s_red[16][17];
  __shared__ float s_m[16], s_isd[16];
  __shared__ float s_xn[16][257];

  float acc[16];
#pragma unroll
  for (int j = 0; j < 16; ++j) acc[j] = 0.f;

  for (int cc = 0; cc < 64; cc += 2) {
    __syncthreads();
    // stage weights COALESCED: per co, 18 contiguous floats (2 ci x 9 k)
    for (int i = t; i < 256 * 18; i += 256) {
      int co = i / 18, rem = i % 18;
      s_w[rem * 257 + co] = wgt[co * 576 + cc * 9 + rem];
    }
    // stage input: 2 ci x 3 rows x 18 cols (halo zero-padded)
    for (int i = t; i < 2 * 3 * 18; i += 256) {
      int c = i / 54;
      int r = (i / 18) % 3;
      int cw = i % 18;
      int gh = h + r - 1;
      int gw = w0 + cw - 1;
      float v = 0.f;
      if (gh >= 0 && gh < 32 && gw >= 0 && gw < 32)
        v = in[((b * 64 + c + cc) * 32 + gh) * 32 + gw];
      s_in[c][r][cw] = v;
    }
    __syncthreads();
#pragma unroll
    for (int c = 0; c < 2; ++c) {
#pragma unroll
      for (int kh = 0; kh < 3; ++kh) {
        float iv[3];
#pragma unroll
        for (int kw = 0; kw < 3; ++kw) iv[kw] = s_in[c][kh][px + kw];
        const float* wp = &s_w[(c * 9 + kh * 3) * 257 + cg * 16];
#pragma unroll
        for (int kw = 0; kw < 3; ++kw) {
#pragma unroll
          for (int j = 0; j < 16; ++j)
            acc[j] = fmaf(iv[kw], wp[kw * 257 + j], acc[j]);
        }
      }
    }
  }
  // bias + LayerNorm over 256 channels of pixel px
#pragma unroll
  for (int j = 0; j < 16; ++j) acc[j] += bias[cg * 16 + j];
  float psum = 0.f;
#pragma unroll
  for (int j = 0; j < 16; ++j) psum += acc[j];
  s_red[px][cg] = psum;
  __syncthreads();
  if (t < 16) {
    float m = 0.f;
    for (int g = 0; g < 16; ++g) m += s_red[t][g];
    s_m[t] = m * (1.f / 256.f);
  }
  __syncthreads();
  float m = s_m[px];
  float vp = 0.f;
#pragma unroll
  for (int j = 0; j < 16; ++j) {
    float dv = acc[j] - m;
    vp += dv * dv;
  }
  s_red[px][cg] = vp;
  __syncthreads();
  if (t < 16) {
    float v = 0.f;
    for (int g = 0; g < 16; ++g) v += s_red[t][g];
    s_isd[t] = 1.f / sqrtf(v * (1.f / 256.f) + 1e-5f);
  }
  __syncthreads();
  float isd = s_isd[px];
#pragma unroll
  for (int j = 0; j < 16; ++j) s_xn[px][cg * 16 + j] = (acc[j] - m) * isd;
  __syncthreads();
  // K/V projection: thread -> (px, cg); cg 0..7 -> k cols, 8..15 -> v
  const float* wb = (cg < 8) ? wk : wv;
  int d0 = (cg & 7) * 8;
  float a2[8];
#pragma unroll
  for (int j = 0; j < 8; ++j) a2[j] = 0.f;
  for (int c = 0; c < 256; ++c) {
    float xv = s_xn[px][c];
    const float* wr = &wb[c * 64 + d0];
#pragma unroll
    for (int j = 0; j < 8; ++j) a2[j] = fmaf(xv, wr[j], a2[j]);
  }
  int p = h * 32 + w0 + px;
  float* ob = (cg < 8) ? kout : vout;
#pragma unroll
  for (int j = 0; j < 8; ++j) ob[(b * 1024 + p) * 64 + d0 + j] = a2[j];
}

// ---------------------------------------------------------------------------
// Slot init + first q. Block per (b,s) = 224 blocks, 64 threads. (unchanged)
// ---------------------------------------------------------------------------
__global__ __launch_bounds__(64) void slot_init(
    const float* __restrict__ mu, const float* __restrict__ logsig,
    const float* __restrict__ noise, const float* __restrict__ wq,
    double* __restrict__ slots, double* __restrict__ qbuf) {
  int bs = blockIdx.x;
  int d = threadIdx.x;
  int sr = bs % 7;
  __shared__ double ln[64], red[64];
  double s = (double)mu[sr * 64 + d] +
             (double)noise[bs * 64 + d] * exp((double)logsig[sr * 64 + d]);
  slots[bs * 64 + d] = s;
  red[d] = s;
  __syncthreads();
  for (int st = 32; st > 0; st >>= 1) {
    if (d < st) red[d] += red[d + st];
    __syncthreads();
  }
  double m = red[0] * (1.0 / 64.0);
  __syncthreads();
  double dv = s - m;
  red[d] = dv * dv;
  __syncthreads();
  for (int st = 32; st > 0; st >>= 1) {
    if (d < st) red[d] += red[d + st];
    __syncthreads();
  }
  double isd = 1.0 / sqrt(red[0] * (1.0 / 64.0) + 1e-5);
  __syncthreads();
  ln[d] = dv * isd;
  __syncthreads();
  double q = 0.0;
  for (int dd = 0; dd < 64; ++dd) q += ln[dd] * (double)wq[dd * 64 + d];
  qbuf[bs * 64 + d] = q * 0.125;
}

// ---------------------------------------------------------------------------
// Attention logits + softmax over s (+1e-8). One thread per (b,n).
// q staged in LDS; K row loaded as 16x float4 (same d-order f64 accumulation).
// Writes transposed attw[(b*7+s)*1024 + n].
// ---------------------------------------------------------------------------
__global__ __launch_bounds__(256) void attn_softmax(
    const float* __restrict__ kbuf, const double* __restrict__ qbuf,
    double* __restrict__ attw) {
  int bx = blockIdx.x;
  int b = bx >> 2;
  int n0 = (bx & 3) * 256;
  int t = threadIdx.x;
  int n = n0 + t;
  __shared__ double s_q[448];
  for (int i = t; i < 448; i += 256) s_q[i] = qbuf[b * 448 + i];
  __syncthreads();
  float4 kr[16];
  const float4* kp = (const float4*)(kbuf + ((size_t)(b * 1024 + n)) * 64);
#pragma unroll
  for (int i = 0; i < 16; ++i) kr[i] = kp[i];
  double l[7];
#pragma unroll
  for (int s = 0; s < 7; ++s) {
    double acc = 0.0;
    const double* qs = &s_q[s * 64];
#pragma unroll
    for (int i = 0; i < 16; ++i) {
      acc += (double)kr[i].x * qs[i * 4 + 0];
      acc += (double)kr[i].y * qs[i * 4 + 1];
      acc += (double)kr[i].z * qs[i * 4 + 2];
      acc += (double)kr[i].w * qs[i * 4 + 3];
    }
    l[s] = acc;
  }
  double mx = l[0];
#pragma unroll
  for (int s = 1; s < 7; ++s) mx = fmax(mx, l[s]);
  double sum = 0.0;
#pragma unroll
  for (int s = 0; s < 7; ++s) {
    l[s] = exp(l[s] - mx);
    sum += l[s];
  }
  double inv = 1.0 / sum;
#pragma unroll
  for (int s = 0; s < 7; ++s)
    attw[(size_t)(b * 7 + s) * 1024 + n] = l[s] * inv + 1e-8;
}

// ---------------------------------------------------------------------------
// FUSED weighted-mean update + GRU + residual MLP + next q.
// Block per (b,s), 512 threads: 8 n-octants of 128 (more TLP, shorter serial
// chains than the 4x256 version). Phase 2 on wave 0 only.
// ---------------------------------------------------------------------------
__global__ __launch_bounds__(512) void attn_update_slot(
    const double* __restrict__ attw, const float* __restrict__ vbuf,
    const float* __restrict__ gwi, const float* __restrict__ gwh,
    const float* __restrict__ gb, const float* __restrict__ w1,
    const float* __restrict__ b1, const float* __restrict__ w2,
    const float* __restrict__ b2, const float* __restrict__ wq,
    double* __restrict__ slots, double* __restrict__ qbuf) {
  int bs = blockIdx.x;
  int b = bs / 7;
  int t = threadIdx.x;
  int d = t & 63, q = t >> 6;  // q in 0..7
  __shared__ double s_aw[1024];
  __shared__ double part[8][64];
  __shared__ double red[512];
  __shared__ double s_u[64], s_p[64], s_ln[64], s_h[128];
  for (int i = t; i < 1024; i += 512) s_aw[i] = attw[(size_t)bs * 1024 + i];
  __syncthreads();
  red[t] = s_aw[t] + s_aw[t + 512];
  double acc = 0.0;
  const float* vb = vbuf + ((size_t)(b * 1024 + q * 128)) * 64 + d;
  for (int nn = 0; nn < 128; ++nn)
    acc += s_aw[q * 128 + nn] * (double)vb[(size_t)nn * 64];
  part[q][d] = acc;
  __syncthreads();
  for (int st = 256; st > 0; st >>= 1) {
    if (t < st) red[t] += red[t + st];
    __syncthreads();
  }
  double asum = red[0];
  if (t < 64) {
    double u = ((part[0][d] + part[1][d]) + (part[2][d] + part[3][d])) +
               ((part[4][d] + part[5][d]) + (part[6][d] + part[7][d]));
    s_u[d] = u / asum;
    s_p[d] = slots[bs * 64 + d];
  }
  __syncthreads();
  if (t >= 64) return;
  // ---- wave 0 only: GRU + LN + MLP + LN + q ----
  double giz = (double)gb[d], gir = (double)gb[64 + d], gin = (double)gb[128 + d];
  double ghz = 0.0, ghr = 0.0, ghn = 0.0;
  for (int dd = 0; dd < 64; ++dd) {
    double uu = s_u[dd], pp = s_p[dd];
    giz += uu * (double)gwi[dd * 192 + d];
    gir += uu * (double)gwi[dd * 192 + 64 + d];
    gin += uu * (double)gwi[dd * 192 + 128 + d];
    ghz += pp * (double)gwh[dd * 192 + d];
    ghr += pp * (double)gwh[dd * 192 + 64 + d];
    ghn += pp * (double)gwh[dd * 192 + 128 + d];
  }
  double z = 1.0 / (1.0 + exp(-(giz + ghz)));
  double r = 1.0 / (1.0 + exp(-(gir + ghr)));
  double nn2 = tanh(gin + r * ghn);
  double sv = (1.0 - z) * nn2 + z * s_p[d];
  double m = wred_sumd(sv) * (1.0 / 64.0);
  double dv = sv - m;
  double var = wred_sumd(dv * dv) * (1.0 / 64.0);
  s_ln[d] = dv / sqrt(var + 1e-5);
  double h0 = (double)b1[d], h1 = (double)b1[64 + d];
  for (int dd = 0; dd < 64; ++dd) {
    double lv = s_ln[dd];
    h0 += lv * (double)w1[dd * 128 + d];
    h1 += lv * (double)w1[dd * 128 + 64 + d];
  }
  s_h[d] = fmax(h0, 0.0);
  s_h[64 + d] = fmax(h1, 0.0);
  double o = (double)b2[d];
  for (int e = 0; e < 128; ++e) o += s_h[e] * (double)w2[e * 64 + d];
  double s2 = sv + o;
  slots[bs * 64 + d] = s2;
  double m2 = wred_sumd(s2) * (1.0 / 64.0);
  double dv2 = s2 - m2;
  double var2 = wred_sumd(dv2 * dv2) * (1.0 / 64.0);
  s_ln[d] = dv2 / sqrt(var2 + 1e-5);
  double qv = 0.0;
  for (int dd = 0; dd < 64; ++dd) qv += s_ln[dd] * (double)wq[dd * 64 + d];
  qbuf[bs * 64 + d] = qv * 0.125;
}

// ---------------------------------------------------------------------------
// Estimator scores. One thread per (b,s,a). (unchanged)
// ---------------------------------------------------------------------------
__global__ __launch_bounds__(256) void scores_naive(
    const double* __restrict__ slots, const float* __restrict__ we,
    const float* __restrict__ wd, double* __restrict__ sc) {
  int idx = blockIdx.x * 256 + threadIdx.x;  // bs*50 + a
  if (idx >= 224 * 50) return;
  int a = idx % 50, bs = idx / 50;
  double lat[32];
  for (int z = 0; z < 32; ++z) {
    double acc = 0.0;
    for (int dd = 0; dd < 64; ++dd)
      acc += slots[bs * 64 + dd] * (double)we[(a * 64 + dd) * 32 + z];
    lat[z] = acc;
  }
  double sum = 0.0;
  for (int dd = 0; dd < 64; ++dd) {
    double rec = 0.0;
    for (int z = 0; z < 32; ++z) rec += lat[z] * (double)wd[(a * 32 + z) * 64 + dd];
    double df = rec - slots[bs * 64 + dd];
    sum += df * df;
  }
  sc[idx] = -sum;
}

// ---------------------------------------------------------------------------
// Top-3 per (b,s), serial, lowest-index tie-break. (unchanged)
// ---------------------------------------------------------------------------
__global__ __launch_bounds__(256) void topk_naive(const double* __restrict__ sc,
                                                  int* __restrict__ topk) {
  int bs = blockIdx.x * 256 + threadIdx.x;
  if (bs >= 224) return;
  int chosen[3];
  for (int r = 0; r < 3; ++r) {
    double best = -1e300;
    int bi = -1;
    for (int a = 0; a < 50; ++a) {
      bool skip = false;
      for (int rr = 0; rr < r; ++rr)
        if (chosen[rr] == a) skip = true;
      if (skip) continue;
      double v = sc[bs * 50 + a];
      if (v > best) {
        best = v;
        bi = a;
      }
    }
    chosen[r] = bi;
    topk[bs * 3 + r] = bi;
  }
}

// ---------------------------------------------------------------------------
// Expert MLP, one block per token (672 blocks, 256 threads). (unchanged)
// ---------------------------------------------------------------------------
__global__ __launch_bounds__(256) void expert_naive(
    const int* __restrict__ topk, const double* __restrict__ slots,
    const float* __restrict__ win, const float* __restrict__ bin,
    const float* __restrict__ wblk, const float* __restrict__ bblk,
    const float* __restrict__ wout, const float* __restrict__ bout,
    float* __restrict__ outp) {
  int ti = blockIdx.x;  // (b*7+s)*3 + kk
  int a = topk[ti];
  int bs = ti / 3;
  int t = threadIdx.x;
  __shared__ double tok[64], ha[256], hb[256];
  if (t < 64) tok[t] = slots[bs * 64 + t];
  __syncthreads();
  double acc = (double)bin[a * 256 + t];
  for (int dd = 0; dd < 64; ++dd)
    acc += tok[dd] * (double)win[(a * 64 + dd) * 256 + t];
  ha[t] = fmax(acc, 0.0);
  __syncthreads();
  double* cur = ha;
  double* nxt = hb;
  for (int i = 0; i < 3; ++i) {
    double a2 = cur[t] + (double)bblk[(a * 3 + i) * 256 + t];
    for (int hh = 0; hh < 256; ++hh)
      a2 += cur[hh] * (double)wblk[((a * 3 + i) * 256 + hh) * 256 + t];
    nxt[t] = fmax(a2, 0.0);
    __syncthreads();
    double* tmp = cur;
    cur = nxt;
    nxt = tmp;
  }
  if (t < 128) {
    double a3 = (double)bout[a * 128 + t];
    for (int hh = 0; hh < 256; ++hh)
      a3 += cur[hh] * (double)wout[(a * 256 + hh) * 128 + t];
    outp[ti * 128 + t] = (float)a3;
  }
}

// ---------------------------------------------------------------------------
extern "C" void kernel_launch(void* const* d_in, const int* in_sizes, int n_in,
                              void* d_out, int out_size, void* d_ws,
                              size_t ws_size, hipStream_t stream) {
  (void)in_sizes; (void)n_in; (void)out_size; (void)ws_size;
  const float* images = (const float*)d_in[0];
  const float* noise = (const float*)d_in[1];
  const float* enc_w0 = (const float*)d_in[2];
  const float* enc_b0 = (const float*)d_in[3];
  const float* enc_w = (const float*)d_in[4];
  const float* enc_b = (const float*)d_in[5];
  const float* enc_wo = (const float*)d_in[6];
  const float* enc_bo = (const float*)d_in[7];
  const float* wk = (const float*)d_in[8];
  const float* wv = (const float*)d_in[9];
  const float* wq = (const float*)d_in[10];
  const float* gru_wi = (const float*)d_in[11];
  const float* gru_wh = (const float*)d_in[12];
  const float* gru_b = (const float*)d_in[13];
  const float* mlp_w1 = (const float*)d_in[14];
  const float* mlp_b1 = (const float*)d_in[15];
  const float* mlp_w2 = (const float*)d_in[16];
  const float* mlp_b2 = (const float*)d_in[17];
  const float* mu = (const float*)d_in[18];
  const float* logsig = (const float*)d_in[19];
  const float* est_we = (const float*)d_in[20];
  const float* est_wd = (const float*)d_in[21];
  const float* ag_win = (const float*)d_in[22];
  const float* ag_bin = (const float*)d_in[23];
  const float* ag_wblk = (const float*)d_in[24];
  const float* ag_bblk = (const float*)d_in[25];
  const float* ag_wout = (const float*)d_in[26];
  const float* ag_bout = (const float*)d_in[27];

  // Workspace layout — byte-identical to the passing round-5/8/9 layout
  double* dws = (double*)d_ws;
  double* slots = dws;                  // 14336
  double* qbuf = slots + 14336;         // 14336
  double* upd = qbuf + 14336;           // 14336 (unused, kept for layout)
  double* attw = upd + 14336;           // 229376 (= 224*1024, [bs][n])
  double* sc = attw + 229376;           // 11200
  int* topk = (int*)(sc + 11200);       // 672 (pad to 1024)
  float* xA = (float*)(topk + 1024);    // 2097152 floats
  float* xB = xA + 2097152;             // 2097152
  float* vbuf = xB + 2097152;           // 2097152

  conv3x3_kernel<3, true><<<256, 256, 0, stream>>>(images, enc_w0, enc_b0, xA, 64, 1);
  conv3x3_kernel<64, true><<<256, 256, 0, stream>>>(xA, enc_w, enc_b, xB, 64, 1);
  conv3x3_kernel<64, true><<<256, 256, 0, stream>>>(xB, enc_w + 36864, enc_b + 64, xA, 64, 1);
  conv3x3_kernel<64, true><<<256, 256, 0, stream>>>(xA, enc_w + 73728, enc_b + 128, xB, 64, 1);
  // fused conv5 + LN + K/V: reads xB, writes k->xA, v->vbuf
  conv5_ln_kv_fused<<<2048, 256, 0, stream>>>(xB, enc_wo, enc_bo, wk, wv, xA, vbuf);
  slot_init<<<224, 64, 0, stream>>>(mu, logsig, noise, wq, slots, qbuf);
  for (int it = 0; it < 3; ++it) {
    attn_softmax<<<128, 256, 0, stream>>>(xA, qbuf, attw);
    attn_update_slot<<<224, 512, 0, stream>>>(attw, vbuf, gru_wi, gru_wh,
                                              gru_b, mlp_w1, mlp_b1, mlp_w2,
                                              mlp_b2, wq, slots, qbuf);
  }
  scores_naive<<<44, 256, 0, stream>>>(slots, est_we, est_wd, sc);
  topk_naive<<<1, 256, 0, stream>>>(sc, topk);
  expert_naive<<<672, 256, 0, stream>>>(topk, slots, ag_win, ag_bin, ag_wblk,
                                        ag_bblk, ag_wout, ag_bout,
                                        (float*)d_out);
}